// Round 1
// baseline (181.167 us; speedup 1.0000x reference)
//
#include <hip/hip_runtime.h>
#include <cstdint>

#define BTOT 4096
#define NBLK 1366   // ceil(4096/3)
#define CT   40     // time-chunk
#define NCH  25     // 1000/40

__device__ __forceinline__ void gload_lds16(const void* g, void* l) {
  __builtin_amdgcn_global_load_lds(
      (const __attribute__((address_space(1))) void*)g,
      (__attribute__((address_space(3))) void*)l, 16, 0, 0);
}

__device__ __forceinline__ float comp4(float4 v, int dt) {
  return dt == 0 ? v.x : dt == 1 ? v.y : dt == 2 ? v.z : v.w;
}

// One wave per block. Lanes 0..59 = 3 batch groups x 20 neurons; lanes 60..63 idle dups.
// LDS: sm[0..3583]  = two x-staging buffers [2][1792] (layout [g][l][tc=40], padded)
//      sm[3584..6143] = LUT[4][32][20]: nibble-sums of W2 columns.
__global__ __launch_bounds__(64)
void snn_kernel(const float* __restrict__ x, const float* __restrict__ W1,
                const float* __restrict__ W2, const float* __restrict__ W3,
                float* __restrict__ out) {
  __shared__ __align__(16) float sm[6144];
  float* lutf = sm + 3584;
  const int lane = threadIdx.x;
  const int bid  = blockIdx.x;

  // Build LUT: lutf[g4*640 + m*20 + i] = sum_{k: m has bit k} W2[i][5*g4+k]
  for (int idx = lane; idx < 2560; idx += 64) {
    int g4  = idx / 640;
    int rem = idx - g4 * 640;
    int m   = rem / 20;
    int i   = rem - m * 20;
    float s = 0.f;
    #pragma unroll
    for (int k = 0; k < 5; ++k)
      if (m & (1 << k)) s += W2[i * 20 + g4 * 5 + k];
    lutf[idx] = s;
  }

  const int  g3     = lane / 20;            // 0..3
  const int  g      = g3 < 3 ? g3 : 2;      // clamp idle lanes onto group 2
  const int  i      = lane - g * 20;        // 0..19 (20..23 for idle lanes)
  const int  i19    = i < 20 ? i : 19;
  const bool active = (g3 < 3);
  const long b      = (long)bid * 3 + g;
  const bool bvalid = (b < BTOT);

  float w1r[14];
  #pragma unroll
  for (int l = 0; l < 14; ++l) w1r[l] = W1[i19 * 14 + l];

  float v1 = 0.f, v2 = 0.f, aacc = 0.f;
  const unsigned sh = 20u * (unsigned)g;

  __syncthreads();  // LUT ready

  // Stage chunk c (40 timesteps of all 3 batches' 14 inputs) into buffer buf.
  // Flat LDS dword index f4 = it*256 + lane*4 maps to (g,l,tc): row=f4/40, tc=f4%40.
  auto stage = [&](int c, int buf) {
    const int t0 = c * CT;
    #pragma unroll
    for (int it = 0; it < 7; ++it) {
      int f4 = it * 256 + lane * 4;
      if (f4 > 1676) f4 = 1676;           // clamp tail; dups land in pad region
      int  row = f4 / 40;
      int  tc  = f4 - row * 40;
      int  gg  = row / 14;
      int  l   = row - gg * 14;
      long bb  = (long)bid * 3 + gg;
      if (bb > BTOT - 1) bb = BTOT - 1;
      const float* src = x + (bb * 14 + l) * 1000 + t0 + tc;
      gload_lds16(src, sm + buf * 1792 + it * 256);
    }
  };

  stage(0, 0);
  for (int c = 0; c < NCH; ++c) {
    const int cur = c & 1;
    if (c + 1 < NCH) {
      stage(c + 1, cur ^ 1);
      asm volatile("s_waitcnt vmcnt(7)" ::: "memory");  // current buf done, next in flight
    } else {
      asm volatile("s_waitcnt vmcnt(0)" ::: "memory");
    }
    const float* xg = sm + cur * 1792 + g * 560;

    for (int tc4 = 0; tc4 < 10; ++tc4) {
      float4 xr[14];
      #pragma unroll
      for (int l = 0; l < 14; ++l)
        xr[l] = *(const float4*)(xg + l * 40 + tc4 * 4);  // ds_read_b128, broadcast in-group

      #pragma unroll
      for (int dt = 0; dt < 4; ++dt) {
        float h1 = 0.f;
        #pragma unroll
        for (int l = 0; l < 14; ++l) h1 = fmaf(w1r[l], comp4(xr[l], dt), h1);

        // LIF layer 1 (decay_input, hard reset)
        v1 = v1 + (h1 - v1) * 0.5f;
        const bool sp1 = (v1 >= 5.0f);
        v1 = sp1 ? 0.f : v1;

        // exchange spikes: wave ballot -> 20-bit group mask
        const unsigned long long bal = __ballot(sp1);
        const unsigned m = (unsigned)(bal >> sh) & 0xFFFFFu;

        // h2[i] = sum_j W2[i][j]*s1[j] via 4 nibble LUTs
        float h2 = lutf[        ( m         & 31u) * 20 + i19]
                 + lutf[ 640 +  ((m >> 5)   & 31u) * 20 + i19]
                 + lutf[1280 +  ((m >> 10)  & 31u) * 20 + i19]
                 + lutf[1920 +  ((m >> 15)  & 31u) * 20 + i19];

        // LIF layer 2
        v2 = v2 + (h2 - v2) * 0.5f;
        const bool sp2 = (v2 >= 5.0f);
        v2 = sp2 ? 0.f : v2;

        // layer-3 closed form: a = (a + s2)/2 ;  v3_final = W3 @ a
        aacc = (aacc + (sp2 ? 1.0f : 0.0f)) * 0.5f;
      }
    }
  }

  // Epilogue: out[b][k] = exp( sum_j W3[k][j] * a[j] )
  __syncthreads();
  if (active) sm[g * 20 + i] = aacc;
  __syncthreads();
  if (active && bvalid) {
    float ar[20];
    #pragma unroll
    for (int j = 0; j < 20; ++j) ar[j] = sm[g * 20 + j];
    for (int q = 0; q < 25; ++q) {
      const int k = i + 20 * q;            // 20 consecutive outputs per group per q
      float acc = 0.f;
      #pragma unroll
      for (int j = 0; j < 20; ++j) acc = fmaf(W3[k * 20 + j], ar[j], acc);
      out[b * 500 + k] = expf(acc);
    }
  }
}

extern "C" void kernel_launch(void* const* d_in, const int* in_sizes, int n_in,
                              void* d_out, int out_size, void* d_ws, size_t ws_size,
                              hipStream_t stream) {
  const float* x  = (const float*)d_in[0];
  const float* W1 = (const float*)d_in[1];
  const float* W2 = (const float*)d_in[2];
  const float* W3 = (const float*)d_in[3];
  float* out = (float*)d_out;
  snn_kernel<<<dim3(NBLK), dim3(64), 0, stream>>>(x, W1, W2, W3, out);
}

// Round 2
// 166.920 us; speedup vs baseline: 1.0854x; 1.0854x over previous
//
#include <hip/hip_runtime.h>
#include <cstdint>

#define BTOT 4096
#define NBLK 1366   // ceil(4096/3)
#define CT   40     // time-chunk
#define NCH  25     // 1000/40

typedef float f32x2 __attribute__((ext_vector_type(2)));

__device__ __forceinline__ void gload_lds16(const void* g, void* l) {
  __builtin_amdgcn_global_load_lds(
      (const __attribute__((address_space(1))) void*)g,
      (__attribute__((address_space(3))) void*)l, 16, 0, 0);
}

// One wave per block. Lanes 0..59 = 3 batch groups x 20 neurons; lanes 60..63 idle dups.
// LDS: sm[0..3583]   = two x-staging buffers [2][1792] (layout [g][l][tc=40], padded)
//      sm[3584..6143] = LUT[4][32][20]: nibble-sums of W2 columns, PRE-SCALED by 0.5.
__global__ __launch_bounds__(64)
void snn_kernel(const float* __restrict__ x, const float* __restrict__ W1,
                const float* __restrict__ W2, const float* __restrict__ W3,
                float* __restrict__ out) {
  __shared__ __align__(16) float sm[6144];
  float* lutf = sm + 3584;
  const int lane = threadIdx.x;
  const int bid  = blockIdx.x;

  // Build LUT: lutf[q*640 + m*20 + i] = 0.5 * sum_{k: m has bit k} W2[i][5*q+k]
  for (int idx = lane; idx < 2560; idx += 64) {
    int q   = idx / 640;
    int rem = idx - q * 640;
    int m   = rem / 20;
    int i   = rem - m * 20;
    float s = 0.f;
    #pragma unroll
    for (int k = 0; k < 5; ++k)
      if (m & (1 << k)) s += W2[i * 20 + q * 5 + k];
    lutf[idx] = 0.5f * s;
  }

  const int  g3     = lane / 20;            // 0..3
  const int  g      = g3 < 3 ? g3 : 2;      // clamp idle lanes onto group 2
  const int  i      = lane - g * 20;        // 0..19 (20..23 for idle lanes)
  const int  i19    = i < 20 ? i : 19;
  const bool active = (g3 < 3);
  const long b      = (long)bid * 3 + g;
  const bool bvalid = (b < BTOT);

  // W1 row, pre-scaled by 0.5, splatted into f32x2 for packed FMA over dt-pairs.
  f32x2 wsp[14];
  #pragma unroll
  for (int l = 0; l < 14; ++l) {
    float w = 0.5f * W1[i19 * 14 + l];
    wsp[l] = (f32x2){w, w};
  }

  float v1 = 0.f, v2 = 0.f, aacc = 0.f;
  const unsigned sh = 20u * (unsigned)g;

  __syncthreads();  // LUT ready

  // Stage chunk c (40 timesteps of all 3 batches' 14 inputs) into buffer buf.
  auto stage = [&](int c, int buf) {
    const int t0 = c * CT;
    #pragma unroll
    for (int it = 0; it < 7; ++it) {
      int f4 = it * 256 + lane * 4;
      if (f4 > 1676) f4 = 1676;           // clamp tail; dups land in pad region
      int  row = f4 / 40;
      int  tc  = f4 - row * 40;
      int  gg  = row / 14;
      int  l   = row - gg * 14;
      long bb  = (long)bid * 3 + gg;
      if (bb > BTOT - 1) bb = BTOT - 1;
      const float* src = x + (bb * 14 + l) * 1000 + t0 + tc;
      gload_lds16(src, sm + buf * 1792 + it * 256);
    }
  };

  stage(0, 0);
  for (int c = 0; c < NCH; ++c) {
    const int cur = c & 1;
    if (c + 1 < NCH) {
      stage(c + 1, cur ^ 1);
      asm volatile("s_waitcnt vmcnt(7)" ::: "memory");  // current buf done, next in flight
    } else {
      asm volatile("s_waitcnt vmcnt(0)" ::: "memory");
    }
    const float* xg = sm + cur * 1792 + g * 560;

    for (int tc4 = 0; tc4 < 10; ++tc4) {
      // ---- load 4 timesteps of x for this group (broadcast within group) ----
      float4 xr[14];
      #pragma unroll
      for (int l = 0; l < 14; ++l)
        xr[l] = *(const float4*)(xg + l * 40 + tc4 * 4);  // ds_read_b128

      // ---- Phase A: h1 (packed over dt pairs) + v1 chain + ballots ----
      f32x2 h01 = {0.f, 0.f}, h23 = {0.f, 0.f};
      #pragma unroll
      for (int l = 0; l < 14; ++l) {
        f32x2 x01 = {xr[l].x, xr[l].y};
        f32x2 x23 = {xr[l].z, xr[l].w};
        h01 = __builtin_elementwise_fma(wsp[l], x01, h01);  // v_pk_fma_f32
        h23 = __builtin_elementwise_fma(wsp[l], x23, h23);
      }
      float h1v[4] = {h01.x, h01.y, h23.x, h23.y};

      unsigned mk[4];
      #pragma unroll
      for (int dt = 0; dt < 4; ++dt) {
        v1 = fmaf(v1, 0.5f, h1v[dt]);   // v' = v/2 + h/2 (W1 pre-scaled)
        const bool sp1 = (v1 >= 5.0f);
        v1 = sp1 ? 0.f : v1;
        const unsigned long long bal = __ballot(sp1);
        mk[dt] = (unsigned)(bal >> sh); // bits >19 are junk; bfe below masks
      }

      // ---- Phase B: all 16 LUT loads issued back-to-back ----
      float hq[16];
      #pragma unroll
      for (int dt = 0; dt < 4; ++dt) {
        #pragma unroll
        for (int q = 0; q < 4; ++q)
          hq[dt * 4 + q] =
              lutf[q * 640 + ((mk[dt] >> (5 * q)) & 31u) * 20 + i19];
      }

      // ---- Phase C: v2 / aacc chain ----
      #pragma unroll
      for (int dt = 0; dt < 4; ++dt) {
        const float h2 = (hq[dt * 4 + 0] + hq[dt * 4 + 1]) +
                         (hq[dt * 4 + 2] + hq[dt * 4 + 3]);  // already *0.5
        v2 = fmaf(v2, 0.5f, h2);
        const bool sp2 = (v2 >= 5.0f);
        v2 = sp2 ? 0.f : v2;
        aacc = fmaf(aacc, 0.5f, sp2 ? 0.5f : 0.f);
      }
    }
  }

  // Epilogue: out[b][k] = exp( sum_j W3[k][j] * a[j] )
  __syncthreads();
  if (active) sm[g * 20 + i] = aacc;
  __syncthreads();
  if (active && bvalid) {
    float ar[20];
    #pragma unroll
    for (int j = 0; j < 20; ++j) ar[j] = sm[g * 20 + j];
    for (int q = 0; q < 25; ++q) {
      const int k = i + 20 * q;
      float acc = 0.f;
      #pragma unroll
      for (int j = 0; j < 20; ++j) acc = fmaf(W3[k * 20 + j], ar[j], acc);
      out[b * 500 + k] = expf(acc);
    }
  }
}

extern "C" void kernel_launch(void* const* d_in, const int* in_sizes, int n_in,
                              void* d_out, int out_size, void* d_ws, size_t ws_size,
                              hipStream_t stream) {
  const float* x  = (const float*)d_in[0];
  const float* W1 = (const float*)d_in[1];
  const float* W2 = (const float*)d_in[2];
  const float* W3 = (const float*)d_in[3];
  float* out = (float*)d_out;
  snn_kernel<<<dim3(NBLK), dim3(64), 0, stream>>>(x, W1, W2, W3, out);
}